// Round 19
// baseline (129.371 us; speedup 1.0000x reference)
//
#include <hip/hip_runtime.h>

typedef unsigned short u16;
typedef unsigned int u32;
typedef __attribute__((ext_vector_type(8))) short bf16x8;
typedef __attribute__((ext_vector_type(4))) float f32x4;

static __device__ __forceinline__ void mfma16(f32x4& c, bf16x8 a, bf16x8 b) {
  asm("v_mfma_f32_16x16x32_bf16 %0, %1, %2, %0" : "+v"(c) : "v"(a), "v"(b));
}
static __device__ __forceinline__ float exp2_fast(float x) {
  float r; asm("v_exp_f32 %0, %1" : "=v"(r) : "v"(x)); return r;
}
static __device__ __forceinline__ u32 cvt_pk_bf16(float lo, float hi) {
  u32 r; asm("v_cvt_pk_bf16_f32 %0, %1, %2" : "=v"(r) : "v"(lo), "v"(hi)); return r;
}

static __device__ __forceinline__ float bfly_sum(float x) {  // reduce over g
  x += __shfl_xor(x, 16);
  x += __shfl_xor(x, 32);
  return x;
}

static __device__ __forceinline__ u16 f2bf(float f) {  // RTNE
  union { float f; u32 u; } v; v.f = f;
  u32 r = v.u + 0x7fffu + ((v.u >> 16) & 1u);
  return (u16)(r >> 16);
}

typedef __attribute__((address_space(1))) void as1_v;
typedef __attribute__((address_space(3))) void as3_v;
static __device__ __forceinline__ void gload16(const u16* g, u16* l) {
  __builtin_amdgcn_global_load_lds((as1_v*)g, (as3_v*)l, 16, 0, 0);
}

// -------- fused prep: x->bf16 + both weight transposes in ONE launch --------
__global__ __launch_bounds__(256) void prep_fused(const float* __restrict__ x,
                                                  u16* __restrict__ xb,
                                                  const float* __restrict__ Wqkv,
                                                  u16* __restrict__ WqkvT,
                                                  const float* __restrict__ Wout,
                                                  u16* __restrict__ WoutT) {
  __shared__ float tile[32][33];
  const int blk = blockIdx.x;
  const int tid = threadIdx.x;
  if (blk >= 4096) {  // cvt x -> xb (float4 per thread)
    const int i = (blk - 4096) * 256 + tid;
    float4 f = ((const float4*)x)[i];
    ushort4 u;
    u.x = f2bf(f.x); u.y = f2bf(f.y); u.z = f2bf(f.z); u.w = f2bf(f.w);
    ((ushort4*)xb)[i] = u;
    return;
  }
  const float* W;
  u16* Wt;
  int Nc, bxi, byi;
  if (blk < 3072) {
    W = Wqkv; Wt = WqkvT; Nc = 3072; bxi = blk % 96; byi = blk / 96;
  } else {
    W = Wout; Wt = WoutT; Nc = 1024;
    const int q = blk - 3072; bxi = q & 31; byi = q >> 5;
  }
  const int K = 1024;
  const int nb = bxi * 32, kb = byi * 32;
  const int tx = tid & 31, ty = tid >> 5;
  for (int i = ty; i < 32; i += 8)
    tile[i][tx] = W[(size_t)(kb + i) * Nc + nb + tx];
  __syncthreads();
  for (int i = ty; i < 32; i += 8)
    Wt[(size_t)(nb + i) * K + kb + tx] = f2bf(tile[tx][i]);
}

// ---------------- GEMM1: 256x256 tile, 8 waves, 2-phase double-buffer ----------------
// Parameter-rescale of the proven 128^2 structure: wave (wr,wc) = (wid>>2,
// wid&3) owns 128x64 output (acc[8][4]); 12 LDS reads feed 32 MFMAs per wave
// per K-step. Grid 192 = one balanced round. V-column tiles (n0 >= 2048)
// write directly to vt[bh][dh][n]; Q cols scaled by qscale. Bijective XCD
// swizzle (192 = 8 x 24). K-accumulation order identical to the 128^2 kernel.
__global__ __launch_bounds__(512, 2) void gemm_bt_256(const u16* __restrict__ A,
                                                      const u16* __restrict__ Bt,
                                                      const float* __restrict__ bias,
                                                      u16* __restrict__ C,
                                                      u16* __restrict__ vtout,
                                                      int M, int N, int K,
                                                      float qscale, int qcols) {
  __shared__ u16 lA[2][8192];  // [256][32] x2
  __shared__ u16 lB[2][8192];
  const int tid = threadIdx.x;
  const int lane = tid & 63, wid = tid >> 6;
  const int l15 = lane & 15, g = lane >> 4;
  const int nbx = N >> 8;
  const int per = ((M >> 8) * nbx) >> 3;
  const int gg = (blockIdx.x & 7) * per + (blockIdx.x >> 3);
  const int bx = gg % nbx, by = gg / nbx;
  const int m0 = by << 8, n0 = bx << 8;
  const int wr = wid >> 2, wc = wid & 3;

  // staging: issue i covers rows i*128..i*128+127; thread -> (row tid>>2, col (tid&3)*8)
  const int srow = tid >> 2;
  const int scol = (tid & 3) << 3;
  const u16* gA0 = A + (size_t)(m0 + srow) * K + scol;
  const u16* gA1 = A + (size_t)(m0 + 128 + srow) * K + scol;
  const u16* gB0 = Bt + (size_t)(n0 + srow) * K + scol;
  const u16* gB1 = Bt + (size_t)(n0 + 128 + srow) * K + scol;

  const int rdA = (wr * 128 + l15) * 32 + g * 8;
  const int rdB = (wc * 64 + l15) * 32 + g * 8;

  f32x4 acc[8][4] = {};

  gload16(gA0, &lA[0][tid * 8]);
  gload16(gA1, &lA[0][4096 + tid * 8]);
  gload16(gB0, &lB[0][tid * 8]);
  gload16(gB1, &lB[0][4096 + tid * 8]);
  __syncthreads();

  const int nk = K >> 5;
  for (int t = 0; t < nk; ++t) {
    const int cur = t & 1, nxt = cur ^ 1;
    if (t + 1 < nk) {
      const int k0 = (t + 1) << 5;
      gload16(gA0 + k0, &lA[nxt][tid * 8]);
      gload16(gA1 + k0, &lA[nxt][4096 + tid * 8]);
      gload16(gB0 + k0, &lB[nxt][tid * 8]);
      gload16(gB1 + k0, &lB[nxt][4096 + tid * 8]);
    }
    bf16x8 aF[8], bF[4];
#pragma unroll
    for (int m = 0; m < 8; ++m) aF[m] = *(const bf16x8*)(&lA[cur][rdA + m * 512]);
#pragma unroll
    for (int n = 0; n < 4; ++n) bF[n] = *(const bf16x8*)(&lB[cur][rdB + n * 512]);
#pragma unroll
    for (int m = 0; m < 8; ++m)
#pragma unroll
      for (int n = 0; n < 4; ++n) mfma16(acc[m][n], aF[m], bF[n]);
    __syncthreads();
  }

  if (n0 >= 2048) {
    // V columns: write directly as vt[bh = b*16+h][dh][nn]
#pragma unroll
    for (int n = 0; n < 4; ++n) {
      const int col = n0 + wc * 64 + n * 16 + l15;
      const float bv = bias[col];
      const int vcol = col - 2048;
      const int hh = vcol >> 6, dh = vcol & 63;
#pragma unroll
      for (int m = 0; m < 8; ++m) {
        const int rbase = m0 + wr * 128 + m * 16 + g * 4;
        const int bb = rbase >> 11, nn = rbase & 2047;
        ushort4 o;
        o.x = f2bf(acc[m][n][0] + bv);
        o.y = f2bf(acc[m][n][1] + bv);
        o.z = f2bf(acc[m][n][2] + bv);
        o.w = f2bf(acc[m][n][3] + bv);
        *(ushort4*)(vtout + (size_t)((bb << 4) | hh) * 131072 +
                    (size_t)dh * 2048 + nn) = o;
      }
    }
    return;
  }

#pragma unroll
  for (int n = 0; n < 4; ++n) {
    const int col = n0 + wc * 64 + n * 16 + l15;
    const float bv = bias[col];
    const float sc = (col < qcols) ? qscale : 1.0f;
#pragma unroll
    for (int m = 0; m < 8; ++m) {
      const int rbase = m0 + wr * 128 + m * 16 + g * 4;
#pragma unroll
      for (int r = 0; r < 4; ++r)
        C[(size_t)(rbase + r) * N + col] = f2bf((acc[m][n][r] + bv) * sc);
    }
  }
}

// ------- GEMM variant: 128x64 tile (2 blocks/CU for GEMM2, r15-proven) -------
__global__ __launch_bounds__(256) void gemm_bt_n64(const u16* __restrict__ A,
                                                   const u16* __restrict__ Bt,
                                                   const float* __restrict__ bias,
                                                   float* __restrict__ C,
                                                   int M, int N, int K) {
  __shared__ u16 lA[2][4096];  // [128][32] x2
  __shared__ u16 lB[2][2048];  // [64][32]  x2
  const int tid = threadIdx.x;
  const int lane = tid & 63, wid = tid >> 6;
  const int nbx = N >> 6;
  const int per = ((M >> 7) * nbx) >> 3;
  const int g = (blockIdx.x & 7) * per + (blockIdx.x >> 3);
  const int bx = g % nbx, by = g / nbx;
  const int m0 = by << 7, n0 = bx << 6;
  const int wr = wid >> 1, wc = wid & 1;

  const int srow = tid >> 2;
  const int scol = (tid & 3) << 3;
  const u16* gA0 = A + (size_t)(m0 + srow) * K + scol;
  const u16* gA1 = A + (size_t)(m0 + 64 + srow) * K + scol;
  const u16* gB0 = Bt + (size_t)(n0 + srow) * K + scol;  // srow in 0..63

  const int rdA = (wr * 64 + (lane & 15)) * 32 + ((lane >> 4) * 8);
  const int rdB = (wc * 32 + (lane & 15)) * 32 + ((lane >> 4) * 8);

  f32x4 acc[4][2] = {};

  gload16(gA0, &lA[0][tid * 8]);
  gload16(gA1, &lA[0][2048 + tid * 8]);
  gload16(gB0, &lB[0][tid * 8]);
  __syncthreads();

  const int nk = K >> 5;
  for (int t = 0; t < nk; ++t) {
    const int cur = t & 1, nxt = cur ^ 1;
    if (t + 1 < nk) {
      const int k0 = (t + 1) << 5;
      gload16(gA0 + k0, &lA[nxt][tid * 8]);
      gload16(gA1 + k0, &lA[nxt][2048 + tid * 8]);
      gload16(gB0 + k0, &lB[nxt][tid * 8]);
    }
    bf16x8 aF[4], bF[2];
#pragma unroll
    for (int m = 0; m < 4; ++m) aF[m] = *(const bf16x8*)(&lA[cur][rdA + m * 512]);
#pragma unroll
    for (int n = 0; n < 2; ++n) bF[n] = *(const bf16x8*)(&lB[cur][rdB + n * 512]);
#pragma unroll
    for (int m = 0; m < 4; ++m)
#pragma unroll
      for (int n = 0; n < 2; ++n) mfma16(acc[m][n], aF[m], bF[n]);
    __syncthreads();
  }

#pragma unroll
  for (int n = 0; n < 2; ++n) {
    const int col = n0 + wc * 32 + n * 16 + (lane & 15);
    const float bv = bias[col];
#pragma unroll
    for (int m = 0; m < 4; ++m) {
      const int rbase = m0 + wr * 64 + m * 16 + ((lane >> 4) * 4);
#pragma unroll
      for (int r = 0; r < 4; ++r)
        C[(size_t)(rbase + r) * N + col] = acc[m][n][r] + bv;
    }
  }
}

// ---------------- fused flash attention (static-shift softmax, r12 verbatim) ----------------
__global__ __launch_bounds__(256) void attn_kernel(const u16* __restrict__ qkv,
                                                   const u16* __restrict__ vt,
                                                   u16* __restrict__ attn_out) {
  __shared__ u16 lK[2][4096];  // [64 kv][64 dh] swizzled
  __shared__ u16 lV[2][4096];  // [64 dh][64 kv] swizzled

  const int tid = threadIdx.x, lane = tid & 63, w = tid >> 6;
  const int l15 = lane & 15, g = lane >> 4;
  // XCD-clustered bijective swizzle: 1024 = 8 xcd * (32 qt * 4 bh-hi)
  const int bid = blockIdx.x;
  const int tt = bid >> 3;
  const int qt = tt & 31;
  const int bh = ((tt >> 5) << 3) | (bid & 7);
  const int b = bh >> 4, h = bh & 15;

  // Q fragments (pre-scaled by 0.125*log2e in GEMM1 epilogue)
  const size_t rowQ = (size_t)(b * 2048 + qt * 64 + w * 16 + l15);
  const u16* qptr = qkv + rowQ * 3072 + h * 64 + g * 8;
  const bf16x8 qf0 = *(const bf16x8*)(qptr);
  const bf16x8 qf1 = *(const bf16x8*)(qptr + 32);

  // K staging (pre-swizzled source): granules tid, tid+256
  const int r0 = tid >> 3, r1 = 32 + (tid >> 3);
  const int c0 = (tid & 7) ^ ((r0 ^ (r0 >> 3)) & 7);
  const int c1 = (tid & 7) ^ ((r1 ^ (r1 >> 3)) & 7);
  const u16* gk0 = qkv + (size_t)(b * 2048 + r0) * 3072 + 1024 + h * 64 + c0 * 8;
  const u16* gk1 = qkv + (size_t)(b * 2048 + r1) * 3072 + 1024 + h * 64 + c1 * 8;
  const u16* vtb = vt + (size_t)bh * 131072;
  const u16* gv0 = vtb + (size_t)r0 * 2048 + c0 * 8;
  const u16* gv1 = vtb + (size_t)r1 * 2048 + c1 * 8;

  // K frag offsets: permuted rows R(f,l15), swizzled chunks
  int koff[4][2];
#pragma unroll
  for (int f = 0; f < 4; ++f) {
    const int R = 32 * (f >> 1) + 8 * (l15 >> 2) + 4 * ((l15 >> 1) & 1) +
                  2 * (f & 1) + (l15 & 1);
    const int sw = (R ^ (R >> 3)) & 7;
#pragma unroll
    for (int hf = 0; hf < 2; ++hf)
      koff[f][hf] = R * 64 + ((((hf << 2) | g) ^ sw) << 3);
  }
  int voff[4][2];
#pragma unroll
  for (int d = 0; d < 4; ++d) {
    const int R = d * 16 + l15;
    const int sw = (R ^ (R >> 3)) & 7;
#pragma unroll
    for (int kk = 0; kk < 2; ++kk)
      voff[d][kk] = R * 64 + ((((kk << 2) | g) ^ sw) << 3);
  }

  float lp = 0.f;  // lane-local partial row-sum (reduced once in epilogue)
  f32x4 oacc[4] = {};

  // prologue: stage tile 0
  gload16(gk0, &lK[0][tid * 8]);
  gload16(gk1, &lK[0][2048 + tid * 8]);
  gload16(gv0, &lV[0][tid * 8]);
  gload16(gv1, &lV[0][2048 + tid * 8]);
  __syncthreads();

  for (int it = 0; it < 32; ++it) {
    const int cur = it & 1, nxt = cur ^ 1;
    const u16* Kc = lK[cur];
    const u16* Vc = lV[cur];
    if (it + 1 < 32) {  // prefetch next tile (drained by end-of-iter barrier)
      const size_t ko = (size_t)(it + 1) * 64 * 3072;
      const int vo = (it + 1) * 64;
      gload16(gk0 + ko, &lK[nxt][tid * 8]);
      gload16(gk1 + ko, &lK[nxt][2048 + tid * 8]);
      gload16(gv0 + vo, &lV[nxt][tid * 8]);
      gload16(gv1 + vo, &lV[nxt][2048 + tid * 8]);
    }

    // S^T = K_perm @ Q^T  (log2 domain; Q prescaled)
    f32x4 s[4] = {};
#pragma unroll
    for (int f = 0; f < 4; ++f) {
      mfma16(s[f], *(const bf16x8*)(Kc + koff[f][0]), qf0);
      mfma16(s[f], *(const bf16x8*)(Kc + koff[f][1]), qf1);
    }

    // static-shift softmax: P = exp2(S), accumulate lane-local l
#pragma unroll
    for (int f = 0; f < 4; ++f)
#pragma unroll
      for (int r = 0; r < 4; ++r) s[f][r] = exp2_fast(s[f][r]);
    lp += (((s[0][0] + s[0][1]) + (s[0][2] + s[0][3])) +
           ((s[1][0] + s[1][1]) + (s[1][2] + s[1][3]))) +
          (((s[2][0] + s[2][1]) + (s[2][2] + s[2][3])) +
           ((s[3][0] + s[3][1]) + (s[3][2] + s[3][3])));

    // pack P in-register: b-frag elem j <-> kv = 8g + j (+32 for kk=1)
    union { bf16x8 v; u32 u[4]; } p0, p1;
    p0.u[0] = cvt_pk_bf16(s[0][0], s[0][1]);
    p0.u[1] = cvt_pk_bf16(s[1][0], s[1][1]);
    p0.u[2] = cvt_pk_bf16(s[0][2], s[0][3]);
    p0.u[3] = cvt_pk_bf16(s[1][2], s[1][3]);
    p1.u[0] = cvt_pk_bf16(s[2][0], s[2][1]);
    p1.u[1] = cvt_pk_bf16(s[3][0], s[3][1]);
    p1.u[2] = cvt_pk_bf16(s[2][2], s[2][3]);
    p1.u[3] = cvt_pk_bf16(s[3][2], s[3][3]);

    // O^T += V^T @ P^T
#pragma unroll
    for (int d = 0; d < 4; ++d) {
      mfma16(oacc[d], *(const bf16x8*)(Vc + voff[d][0]), p0.v);
      mfma16(oacc[d], *(const bf16x8*)(Vc + voff[d][1]), p1.v);
    }

    __syncthreads();
  }

  // epilogue: reduce l across the 4 kv-groups, then normalize
  const float l_ = bfly_sum(lp);
  const float inv = 1.f / l_;
#pragma unroll
  for (int d = 0; d < 4; ++d)
#pragma unroll
    for (int r = 0; r < 4; ++r)
      attn_out[rowQ * 1024 + h * 64 + d * 16 + g * 4 + r] = f2bf(oacc[d][r] * inv);
}

// ---------------- launcher ----------------
extern "C" void kernel_launch(void* const* d_in, const int* in_sizes, int n_in,
                              void* d_out, int out_size, void* d_ws, size_t ws_size,
                              hipStream_t stream) {
  const float* x    = (const float*)d_in[0];
  const float* Wqkv = (const float*)d_in[1];
  const float* bqkv = (const float*)d_in[2];
  const float* Wout = (const float*)d_in[3];
  const float* bout = (const float*)d_in[4];
  float* out = (float*)d_out;

  char* ws = (char*)d_ws;
  u16* xb    = (u16*)(ws);             // 4096x1024 bf16   @ 0
  u16* WqkvT = (u16*)(ws + 8388608);   // 3072x1024        @ 8M
  u16* WoutT = (u16*)(ws + 14680064);  // 1024x1024        @ 14M
  u16* qkvb  = (u16*)(ws + 16777216);  // 4096x3072        @ 16M (V cols unused)
  u16* attnb = (u16*)(ws + 41943040);  // 4096x1024        @ 40M
  // vt lives in d_out (8 MB of its 16 MB): written by GEMM1 (V cols), read by
  // attn, then d_out is fully overwritten by GEMM2. Temporally disjoint.
  u16* vt = (u16*)d_out;

  prep_fused<<<dim3(8192), 256, 0, stream>>>(x, xb, Wqkv, WqkvT, Wout, WoutT);

  // Q columns pre-scaled by 0.125 * log2(e) -> softmax runs in exp2 domain
  gemm_bt_256<<<dim3(192), 512, 0, stream>>>(xb, WqkvT, bqkv, qkvb, vt,
                                             4096, 3072, 1024, 0.18033688f, 1024);
  attn_kernel<<<dim3(32 * 32), 256, 0, stream>>>(qkvb, vt, attnb);
  gemm_bt_n64<<<dim3(512), 256, 0, stream>>>(attnb, WoutT, bout, out,
                                             4096, 1024, 1024);
}

// Round 20
// 118.958 us; speedup vs baseline: 1.0875x; 1.0875x over previous
//
#include <hip/hip_runtime.h>

typedef unsigned short u16;
typedef unsigned int u32;
typedef __attribute__((ext_vector_type(8))) short bf16x8;
typedef __attribute__((ext_vector_type(4))) float f32x4;

static __device__ __forceinline__ void mfma16(f32x4& c, bf16x8 a, bf16x8 b) {
  asm("v_mfma_f32_16x16x32_bf16 %0, %1, %2, %0" : "+v"(c) : "v"(a), "v"(b));
}
static __device__ __forceinline__ float exp2_fast(float x) {
  float r; asm("v_exp_f32 %0, %1" : "=v"(r) : "v"(x)); return r;
}
static __device__ __forceinline__ u32 cvt_pk_bf16(float lo, float hi) {
  u32 r; asm("v_cvt_pk_bf16_f32 %0, %1, %2" : "=v"(r) : "v"(lo), "v"(hi)); return r;
}

static __device__ __forceinline__ float bfly_sum(float x) {  // reduce over g
  x += __shfl_xor(x, 16);
  x += __shfl_xor(x, 32);
  return x;
}

static __device__ __forceinline__ u16 f2bf(float f) {  // RTNE
  union { float f; u32 u; } v; v.f = f;
  u32 r = v.u + 0x7fffu + ((v.u >> 16) & 1u);
  return (u16)(r >> 16);
}

typedef __attribute__((address_space(1))) void as1_v;
typedef __attribute__((address_space(3))) void as3_v;
static __device__ __forceinline__ void gload16(const u16* g, u16* l) {
  __builtin_amdgcn_global_load_lds((as1_v*)g, (as3_v*)l, 16, 0, 0);
}

// -------- fused prep: x->bf16 + both weight transposes in ONE launch --------
__global__ __launch_bounds__(256) void prep_fused(const float* __restrict__ x,
                                                  u16* __restrict__ xb,
                                                  const float* __restrict__ Wqkv,
                                                  u16* __restrict__ WqkvT,
                                                  const float* __restrict__ Wout,
                                                  u16* __restrict__ WoutT) {
  __shared__ float tile[32][33];
  const int blk = blockIdx.x;
  const int tid = threadIdx.x;
  if (blk >= 4096) {  // cvt x -> xb (float4 per thread)
    const int i = (blk - 4096) * 256 + tid;
    float4 f = ((const float4*)x)[i];
    ushort4 u;
    u.x = f2bf(f.x); u.y = f2bf(f.y); u.z = f2bf(f.z); u.w = f2bf(f.w);
    ((ushort4*)xb)[i] = u;
    return;
  }
  const float* W;
  u16* Wt;
  int Nc, bxi, byi;
  if (blk < 3072) {
    W = Wqkv; Wt = WqkvT; Nc = 3072; bxi = blk % 96; byi = blk / 96;
  } else {
    W = Wout; Wt = WoutT; Nc = 1024;
    const int q = blk - 3072; bxi = q & 31; byi = q >> 5;
  }
  const int K = 1024;
  const int nb = bxi * 32, kb = byi * 32;
  const int tx = tid & 31, ty = tid >> 5;
  for (int i = ty; i < 32; i += 8)
    tile[i][tx] = W[(size_t)(kb + i) * Nc + nb + tx];
  __syncthreads();
  for (int i = ty; i < 32; i += 8)
    Wt[(size_t)(nb + i) * K + kb + tx] = f2bf(tile[tx][i]);
}

// ---------------- GEMM: C[M][N] = A[M][K] @ Bt[N][K]^T + bias ----------------
// 128x128 tile, 2-phase double-buffer + bijective XCD swizzle (r15-proven).
// Blocks with n0 >= 2048 (the V columns of the QKV GEMM) write their output
// DIRECTLY in vt[bh][dh][n] layout (vtout != nullptr) — no separate vtrans.
template <int OUT_F32>
__global__ __launch_bounds__(256) void gemm_bt(const u16* __restrict__ A,
                                               const u16* __restrict__ Bt,
                                               const float* __restrict__ bias,
                                               void* __restrict__ C,
                                               u16* __restrict__ vtout,
                                               int M, int N, int K,
                                               float qscale, int qcols) {
  __shared__ u16 lA[2][4096];  // [128][32] x2
  __shared__ u16 lB[2][4096];
  const int tid = threadIdx.x;
  const int lane = tid & 63, wid = tid >> 6;
  const int nbx = N >> 7;
  const int per = ((M >> 7) * nbx) >> 3;
  const int g = (blockIdx.x & 7) * per + (blockIdx.x >> 3);
  const int bx = g % nbx, by = g / nbx;
  const int m0 = by << 7, n0 = bx << 7;
  const int wr = wid >> 1, wc = wid & 1;

  const int srow = tid >> 2;
  const int scol = (tid & 3) << 3;
  const u16* gA0 = A + (size_t)(m0 + srow) * K + scol;
  const u16* gA1 = A + (size_t)(m0 + 64 + srow) * K + scol;
  const u16* gB0 = Bt + (size_t)(n0 + srow) * K + scol;
  const u16* gB1 = Bt + (size_t)(n0 + 64 + srow) * K + scol;

  const int rdA = (wr * 64 + (lane & 15)) * 32 + ((lane >> 4) * 8);
  const int rdB = (wc * 64 + (lane & 15)) * 32 + ((lane >> 4) * 8);

  f32x4 acc[4][4] = {};

  gload16(gA0, &lA[0][tid * 8]);
  gload16(gA1, &lA[0][2048 + tid * 8]);
  gload16(gB0, &lB[0][tid * 8]);
  gload16(gB1, &lB[0][2048 + tid * 8]);
  __syncthreads();

  const int nk = K >> 5;
  for (int t = 0; t < nk; ++t) {
    const int cur = t & 1, nxt = cur ^ 1;
    if (t + 1 < nk) {
      const int k0 = (t + 1) << 5;
      gload16(gA0 + k0, &lA[nxt][tid * 8]);
      gload16(gA1 + k0, &lA[nxt][2048 + tid * 8]);
      gload16(gB0 + k0, &lB[nxt][tid * 8]);
      gload16(gB1 + k0, &lB[nxt][2048 + tid * 8]);
    }
    bf16x8 aF[4], bF[4];
#pragma unroll
    for (int m = 0; m < 4; ++m) aF[m] = *(const bf16x8*)(&lA[cur][rdA + m * 512]);
#pragma unroll
    for (int n = 0; n < 4; ++n) bF[n] = *(const bf16x8*)(&lB[cur][rdB + n * 512]);
#pragma unroll
    for (int m = 0; m < 4; ++m)
#pragma unroll
      for (int n = 0; n < 4; ++n) mfma16(acc[m][n], aF[m], bF[n]);
    __syncthreads();
  }

  if (vtout != nullptr && n0 >= 2048) {
    // V columns: write directly as vt[bh = b*16+h][dh][nn]
#pragma unroll
    for (int n = 0; n < 4; ++n) {
      const int col = n0 + wc * 64 + n * 16 + (lane & 15);
      const float bv = bias[col];
      const int vcol = col - 2048;
      const int hh = vcol >> 6, dh = vcol & 63;
#pragma unroll
      for (int m = 0; m < 4; ++m) {
        const int rbase = m0 + wr * 64 + m * 16 + ((lane >> 4) * 4);
        const int bb = rbase >> 11, nn = rbase & 2047;  // r=0..3 stay in-batch
        ushort4 o;
        o.x = f2bf(acc[m][n][0] + bv);
        o.y = f2bf(acc[m][n][1] + bv);
        o.z = f2bf(acc[m][n][2] + bv);
        o.w = f2bf(acc[m][n][3] + bv);
        *(ushort4*)(vtout + (size_t)((bb << 4) | hh) * 131072 +
                    (size_t)dh * 2048 + nn) = o;
      }
    }
    return;
  }

#pragma unroll
  for (int n = 0; n < 4; ++n) {
    const int col = n0 + wc * 64 + n * 16 + (lane & 15);
    const float bv = bias[col];
    const float sc = (col < qcols) ? qscale : 1.0f;
#pragma unroll
    for (int m = 0; m < 4; ++m) {
      const int rbase = m0 + wr * 64 + m * 16 + ((lane >> 4) * 4);
#pragma unroll
      for (int r = 0; r < 4; ++r) {
        const float v = (acc[m][n][r] + bv) * sc;
        const size_t idx = (size_t)(rbase + r) * N + col;
        if (OUT_F32) ((float*)C)[idx] = v;
        else         ((u16*)C)[idx] = f2bf(v);
      }
    }
  }
}

// ------- GEMM variant: 128x64 tile (2 blocks/CU for GEMM2, r15-proven) -------
__global__ __launch_bounds__(256) void gemm_bt_n64(const u16* __restrict__ A,
                                                   const u16* __restrict__ Bt,
                                                   const float* __restrict__ bias,
                                                   float* __restrict__ C,
                                                   int M, int N, int K) {
  __shared__ u16 lA[2][4096];  // [128][32] x2
  __shared__ u16 lB[2][2048];  // [64][32]  x2
  const int tid = threadIdx.x;
  const int lane = tid & 63, wid = tid >> 6;
  const int nbx = N >> 6;
  const int per = ((M >> 7) * nbx) >> 3;
  const int g = (blockIdx.x & 7) * per + (blockIdx.x >> 3);
  const int bx = g % nbx, by = g / nbx;
  const int m0 = by << 7, n0 = bx << 6;
  const int wr = wid >> 1, wc = wid & 1;

  const int srow = tid >> 2;
  const int scol = (tid & 3) << 3;
  const u16* gA0 = A + (size_t)(m0 + srow) * K + scol;
  const u16* gA1 = A + (size_t)(m0 + 64 + srow) * K + scol;
  const u16* gB0 = Bt + (size_t)(n0 + srow) * K + scol;  // srow in 0..63

  const int rdA = (wr * 64 + (lane & 15)) * 32 + ((lane >> 4) * 8);
  const int rdB = (wc * 32 + (lane & 15)) * 32 + ((lane >> 4) * 8);

  f32x4 acc[4][2] = {};

  gload16(gA0, &lA[0][tid * 8]);
  gload16(gA1, &lA[0][2048 + tid * 8]);
  gload16(gB0, &lB[0][tid * 8]);
  __syncthreads();

  const int nk = K >> 5;
  for (int t = 0; t < nk; ++t) {
    const int cur = t & 1, nxt = cur ^ 1;
    if (t + 1 < nk) {
      const int k0 = (t + 1) << 5;
      gload16(gA0 + k0, &lA[nxt][tid * 8]);
      gload16(gA1 + k0, &lA[nxt][2048 + tid * 8]);
      gload16(gB0 + k0, &lB[nxt][tid * 8]);
    }
    bf16x8 aF[4], bF[2];
#pragma unroll
    for (int m = 0; m < 4; ++m) aF[m] = *(const bf16x8*)(&lA[cur][rdA + m * 512]);
#pragma unroll
    for (int n = 0; n < 2; ++n) bF[n] = *(const bf16x8*)(&lB[cur][rdB + n * 512]);
#pragma unroll
    for (int m = 0; m < 4; ++m)
#pragma unroll
      for (int n = 0; n < 2; ++n) mfma16(acc[m][n], aF[m], bF[n]);
    __syncthreads();
  }

#pragma unroll
  for (int n = 0; n < 2; ++n) {
    const int col = n0 + wc * 32 + n * 16 + (lane & 15);
    const float bv = bias[col];
#pragma unroll
    for (int m = 0; m < 4; ++m) {
      const int rbase = m0 + wr * 64 + m * 16 + ((lane >> 4) * 4);
#pragma unroll
      for (int r = 0; r < 4; ++r)
        C[(size_t)(rbase + r) * N + col] = acc[m][n][r] + bv;
    }
  }
}

// ---------------- fused flash attention (static-shift softmax, r12 verbatim) ----------------
__global__ __launch_bounds__(256) void attn_kernel(const u16* __restrict__ qkv,
                                                   const u16* __restrict__ vt,
                                                   u16* __restrict__ attn_out) {
  __shared__ u16 lK[2][4096];  // [64 kv][64 dh] swizzled
  __shared__ u16 lV[2][4096];  // [64 dh][64 kv] swizzled

  const int tid = threadIdx.x, lane = tid & 63, w = tid >> 6;
  const int l15 = lane & 15, g = lane >> 4;
  // XCD-clustered bijective swizzle: 1024 = 8 xcd * (32 qt * 4 bh-hi)
  const int bid = blockIdx.x;
  const int tt = bid >> 3;
  const int qt = tt & 31;
  const int bh = ((tt >> 5) << 3) | (bid & 7);
  const int b = bh >> 4, h = bh & 15;

  // Q fragments (pre-scaled by 0.125*log2e in GEMM1 epilogue)
  const size_t rowQ = (size_t)(b * 2048 + qt * 64 + w * 16 + l15);
  const u16* qptr = qkv + rowQ * 3072 + h * 64 + g * 8;
  const bf16x8 qf0 = *(const bf16x8*)(qptr);
  const bf16x8 qf1 = *(const bf16x8*)(qptr + 32);

  // K staging (pre-swizzled source): granules tid, tid+256
  const int r0 = tid >> 3, r1 = 32 + (tid >> 3);
  const int c0 = (tid & 7) ^ ((r0 ^ (r0 >> 3)) & 7);
  const int c1 = (tid & 7) ^ ((r1 ^ (r1 >> 3)) & 7);
  const u16* gk0 = qkv + (size_t)(b * 2048 + r0) * 3072 + 1024 + h * 64 + c0 * 8;
  const u16* gk1 = qkv + (size_t)(b * 2048 + r1) * 3072 + 1024 + h * 64 + c1 * 8;
  const u16* vtb = vt + (size_t)bh * 131072;
  const u16* gv0 = vtb + (size_t)r0 * 2048 + c0 * 8;
  const u16* gv1 = vtb + (size_t)r1 * 2048 + c1 * 8;

  // K frag offsets: permuted rows R(f,l15), swizzled chunks
  int koff[4][2];
#pragma unroll
  for (int f = 0; f < 4; ++f) {
    const int R = 32 * (f >> 1) + 8 * (l15 >> 2) + 4 * ((l15 >> 1) & 1) +
                  2 * (f & 1) + (l15 & 1);
    const int sw = (R ^ (R >> 3)) & 7;
#pragma unroll
    for (int hf = 0; hf < 2; ++hf)
      koff[f][hf] = R * 64 + ((((hf << 2) | g) ^ sw) << 3);
  }
  int voff[4][2];
#pragma unroll
  for (int d = 0; d < 4; ++d) {
    const int R = d * 16 + l15;
    const int sw = (R ^ (R >> 3)) & 7;
#pragma unroll
    for (int kk = 0; kk < 2; ++kk)
      voff[d][kk] = R * 64 + ((((kk << 2) | g) ^ sw) << 3);
  }

  float lp = 0.f;  // lane-local partial row-sum (reduced once in epilogue)
  f32x4 oacc[4] = {};

  // prologue: stage tile 0
  gload16(gk0, &lK[0][tid * 8]);
  gload16(gk1, &lK[0][2048 + tid * 8]);
  gload16(gv0, &lV[0][tid * 8]);
  gload16(gv1, &lV[0][2048 + tid * 8]);
  __syncthreads();

  for (int it = 0; it < 32; ++it) {
    const int cur = it & 1, nxt = cur ^ 1;
    const u16* Kc = lK[cur];
    const u16* Vc = lV[cur];
    if (it + 1 < 32) {  // prefetch next tile (drained by end-of-iter barrier)
      const size_t ko = (size_t)(it + 1) * 64 * 3072;
      const int vo = (it + 1) * 64;
      gload16(gk0 + ko, &lK[nxt][tid * 8]);
      gload16(gk1 + ko, &lK[nxt][2048 + tid * 8]);
      gload16(gv0 + vo, &lV[nxt][tid * 8]);
      gload16(gv1 + vo, &lV[nxt][2048 + tid * 8]);
    }

    // S^T = K_perm @ Q^T  (log2 domain; Q prescaled)
    f32x4 s[4] = {};
#pragma unroll
    for (int f = 0; f < 4; ++f) {
      mfma16(s[f], *(const bf16x8*)(Kc + koff[f][0]), qf0);
      mfma16(s[f], *(const bf16x8*)(Kc + koff[f][1]), qf1);
    }

    // static-shift softmax: P = exp2(S), accumulate lane-local l
#pragma unroll
    for (int f = 0; f < 4; ++f)
#pragma unroll
      for (int r = 0; r < 4; ++r) s[f][r] = exp2_fast(s[f][r]);
    lp += (((s[0][0] + s[0][1]) + (s[0][2] + s[0][3])) +
           ((s[1][0] + s[1][1]) + (s[1][2] + s[1][3]))) +
          (((s[2][0] + s[2][1]) + (s[2][2] + s[2][3])) +
           ((s[3][0] + s[3][1]) + (s[3][2] + s[3][3])));

    // pack P in-register: b-frag elem j <-> kv = 8g + j (+32 for kk=1)
    union { bf16x8 v; u32 u[4]; } p0, p1;
    p0.u[0] = cvt_pk_bf16(s[0][0], s[0][1]);
    p0.u[1] = cvt_pk_bf16(s[1][0], s[1][1]);
    p0.u[2] = cvt_pk_bf16(s[0][2], s[0][3]);
    p0.u[3] = cvt_pk_bf16(s[1][2], s[1][3]);
    p1.u[0] = cvt_pk_bf16(s[2][0], s[2][1]);
    p1.u[1] = cvt_pk_bf16(s[3][0], s[3][1]);
    p1.u[2] = cvt_pk_bf16(s[2][2], s[2][3]);
    p1.u[3] = cvt_pk_bf16(s[3][2], s[3][3]);

    // O^T += V^T @ P^T
#pragma unroll
    for (int d = 0; d < 4; ++d) {
      mfma16(oacc[d], *(const bf16x8*)(Vc + voff[d][0]), p0.v);
      mfma16(oacc[d], *(const bf16x8*)(Vc + voff[d][1]), p1.v);
    }

    __syncthreads();
  }

  // epilogue: reduce l across the 4 kv-groups, then normalize
  const float l_ = bfly_sum(lp);
  const float inv = 1.f / l_;
#pragma unroll
  for (int d = 0; d < 4; ++d)
#pragma unroll
    for (int r = 0; r < 4; ++r)
      attn_out[rowQ * 1024 + h * 64 + d * 16 + g * 4 + r] = f2bf(oacc[d][r] * inv);
}

// ---------------- launcher ----------------
extern "C" void kernel_launch(void* const* d_in, const int* in_sizes, int n_in,
                              void* d_out, int out_size, void* d_ws, size_t ws_size,
                              hipStream_t stream) {
  const float* x    = (const float*)d_in[0];
  const float* Wqkv = (const float*)d_in[1];
  const float* bqkv = (const float*)d_in[2];
  const float* Wout = (const float*)d_in[3];
  const float* bout = (const float*)d_in[4];
  float* out = (float*)d_out;

  char* ws = (char*)d_ws;
  u16* xb    = (u16*)(ws);             // 4096x1024 bf16   @ 0
  u16* WqkvT = (u16*)(ws + 8388608);   // 3072x1024        @ 8M
  u16* WoutT = (u16*)(ws + 14680064);  // 1024x1024        @ 14M
  u16* qkvb  = (u16*)(ws + 16777216);  // 4096x3072        @ 16M (V cols unused)
  u16* attnb = (u16*)(ws + 41943040);  // 4096x1024        @ 40M
  // vt lives in d_out (8 MB of its 16 MB): written by GEMM1 (V cols), read by
  // attn, then d_out is fully overwritten by GEMM2. Temporally disjoint.
  u16* vt = (u16*)d_out;

  prep_fused<<<dim3(8192), 256, 0, stream>>>(x, xb, Wqkv, WqkvT, Wout, WoutT);

  // Q columns pre-scaled by 0.125 * log2(e) -> softmax runs in exp2 domain
  gemm_bt<0><<<dim3(24 * 32), 256, 0, stream>>>(xb, WqkvT, bqkv, qkvb, vt,
                                                4096, 3072, 1024, 0.18033688f, 1024);
  attn_kernel<<<dim3(32 * 32), 256, 0, stream>>>(qkvb, vt, attnb);
  gemm_bt_n64<<<dim3(512), 256, 0, stream>>>(attnb, WoutT, bout, out,
                                             4096, 1024, 1024);
}